// Round 1
// 1252.265 us; speedup vs baseline: 1.1791x; 1.1791x over previous
//
#include <hip/hip_runtime.h>

// ---------------------------------------------------------------------------
// MixedFPQuantizedLinear: per-32-block MXFP4 quant of x (fp16 scale) then
// C = x_q @ W^T + bias.  M=8192, K=4096, N=11008, all fp32 in/out.
// R3: GEMM rewritten to the verified 256x256 / BK=64 / 8-wave phase-interleaved
// template (learn_hip m201 class): full 8-chunk XOR LDS swizzle (conflict-free
// ds_read_b128), counted vmcnt (8/2, never 0 in main loop), raw s_barrier +
// lgkmcnt(0) + sched_barrier(0) per phase, setprio(1) around MFMA clusters,
// bijective XCD swizzle (1376 = 8*172). prep kernel unchanged (numerics!).
// ---------------------------------------------------------------------------

#define M_DIM 8192
#define K_DIM 4096
#define N_DIM 11008

typedef float floatx4 __attribute__((ext_vector_type(4)));
typedef _Float16 half8 __attribute__((ext_vector_type(8)));

// ----------------------- fused quant(x) + convert(W) -----------------------

__device__ inline float snap_mxfp4(float a) {
    // grid {0,0.5,1,1.5,2,3,4,6}; ties go to LOWER value (matches ref).
    float lo  = (a <= 0.25f) ? 0.0f : ((a <= 0.75f) ? 0.5f : 1.0f);
    float mid = (a <= 1.75f) ? 1.5f : 2.0f;
    float hi  = (a <= 3.5f)  ? 3.0f : ((a <= 5.0f) ? 4.0f : 6.0f);
    return (a <= 1.25f) ? lo : ((a <= 2.5f) ? mid : hi);
}

#define QUANT_BLOCKS 16384   // 2*4096*4096 / (8*256)
#define CONV_BLOCKS  22016   // 11008*4096 / (8*256)

__global__ __launch_bounds__(256) void prep_kernel(
        const float* __restrict__ x, _Float16* __restrict__ xq,
        const float* __restrict__ W, _Float16* __restrict__ wq) {
    if (blockIdx.x < QUANT_BLOCKS) {
        size_t t    = (size_t)blockIdx.x * 256 + threadIdx.x;
        size_t base = t * 8;
        const float4* p = (const float4*)(x + base);
        float4 v0 = p[0];
        float4 v1 = p[1];
        float in[8] = {v0.x, v0.y, v0.z, v0.w, v1.x, v1.y, v1.z, v1.w};

        float a0 = fmaxf(fmaxf(fabsf(in[0]), fabsf(in[1])), fmaxf(fabsf(in[2]), fabsf(in[3])));
        float a1 = fmaxf(fmaxf(fabsf(in[4]), fabsf(in[5])), fmaxf(fabsf(in[6]), fabsf(in[7])));
        float amax = fmaxf(a0, a1);
        amax = fmaxf(amax, __shfl_xor(amax, 1));
        amax = fmaxf(amax, __shfl_xor(amax, 2));
        amax = fmaxf(amax, 1e-12f);

        float scale = (float)(_Float16)(amax / 6.0f);   // fp16 round-trip like ref
        float sdiv  = fmaxf(scale, 1e-12f);

        union { _Float16 h[8]; uint4 v; } o;
#pragma unroll
        for (int i = 0; i < 8; ++i) {
            float xn = in[i] / sdiv;
            float s  = snap_mxfp4(fabsf(xn));
            o.h[i]   = (_Float16)copysignf(s * scale, xn);
        }
        *(uint4*)(xq + base) = o.v;
    } else {
        size_t t    = (size_t)(blockIdx.x - QUANT_BLOCKS) * 256 + threadIdx.x;
        size_t base = t * 8;
        const float4* p = (const float4*)(W + base);
        float4 v0 = p[0];
        float4 v1 = p[1];
        float in[8] = {v0.x, v0.y, v0.z, v0.w, v1.x, v1.y, v1.z, v1.w};
        union { _Float16 h[8]; uint4 v; } o;
#pragma unroll
        for (int i = 0; i < 8; ++i) o.h[i] = (_Float16)in[i];
        *(uint4*)(wq + base) = o.v;
    }
}

// -------------------------------- GEMM -------------------------------------
// C[m][n] = sum_k A[m][k]*B[n][k] + bias[n].  A=x_q [8192][4096], B=W [11008][4096].
// 256x256 tile, BK=64, 512 threads = 8 waves (2M x 4N), wave owns 128x64 out.
// LDS 128KB: 2 buffers x {A[256][64] , B[256][64]} f16, chunk-linear dest for
// global_load_lds; k-chunk XOR-swizzled c' = c ^ (row&7)  -> conflict-free
// ds_read_b128 (8 lanes per 4-bank group).
// Per K-tile: 4 phases (ks0/mh0, ks0/mh1, ks1/mh1, ks1/mh0), 16 MFMA each.
// Whole next tile (8 loads/thread) issued at P1; waits: vmcnt(8) end-P1
// (retires cur tile's A_h1), vmcnt(2) end-P4 (retires next tile's A_h0+B).
// All waited loads are >=3 phases old -> no stall when L2/L3-warm.

#define M_TILES 32
#define N_TILES 43
#define K_TILES 64

#define GLDS(gp, lo) __builtin_amdgcn_global_load_lds(                        \
    (const __attribute__((address_space(1))) unsigned int*)(const void*)(gp), \
    (__attribute__((address_space(3))) unsigned int*)(void*)(lds + (lo)), 16, 0, 0)

// queue order matters: A_h0(2), B_h0(2), B_h1(2), A_h1(2) -- A_h1 LAST.
#define ISSUE_TILE(bo, ko) do {                        \
    GLDS(aS + (ko),               (bo) +         stW); \
    GLDS(aS + (ko) +  64*K_DIM,   (bo) +  8192 + stW); \
    GLDS(bS + (ko),               (bo) + 32768 + stW); \
    GLDS(bS + (ko) +  64*K_DIM,   (bo) + 40960 + stW); \
    GLDS(bS + (ko) + 128*K_DIM,   (bo) + 49152 + stW); \
    GLDS(bS + (ko) + 192*K_DIM,   (bo) + 57344 + stW); \
    GLDS(aS + (ko) + 128*K_DIM,   (bo) + 16384 + stW); \
    GLDS(aS + (ko) + 192*K_DIM,   (bo) + 24576 + stW); \
  } while (0)

#define LDA(bo, mh, m, cp) (*(const half8*)(lds + (bo) + (mh)*16384 + (m)*2048 + aRd + (cp)))
#define LDB(bo, q,  cp)    (*(const half8*)(lds + (bo) + ((q)>>1)*16384 + ((q)&1)*2048 + bRd + (cp)))

#define BAR()   __builtin_amdgcn_s_barrier()
#define LGKM0() do { asm volatile("s_waitcnt lgkmcnt(0)" ::: "memory");      \
                     __builtin_amdgcn_sched_barrier(0); } while (0)
#define VMW(n)  asm volatile("s_waitcnt vmcnt(" #n ")" ::: "memory")

#define MFMA16(rb) do {                                                                        \
    acc[(rb)+0][0] = __builtin_amdgcn_mfma_f32_16x16x32_f16(a0, b0, acc[(rb)+0][0], 0, 0, 0);  \
    acc[(rb)+1][0] = __builtin_amdgcn_mfma_f32_16x16x32_f16(a1, b0, acc[(rb)+1][0], 0, 0, 0);  \
    acc[(rb)+2][0] = __builtin_amdgcn_mfma_f32_16x16x32_f16(a2, b0, acc[(rb)+2][0], 0, 0, 0);  \
    acc[(rb)+3][0] = __builtin_amdgcn_mfma_f32_16x16x32_f16(a3, b0, acc[(rb)+3][0], 0, 0, 0);  \
    acc[(rb)+0][1] = __builtin_amdgcn_mfma_f32_16x16x32_f16(a0, b1, acc[(rb)+0][1], 0, 0, 0);  \
    acc[(rb)+1][1] = __builtin_amdgcn_mfma_f32_16x16x32_f16(a1, b1, acc[(rb)+1][1], 0, 0, 0);  \
    acc[(rb)+2][1] = __builtin_amdgcn_mfma_f32_16x16x32_f16(a2, b1, acc[(rb)+2][1], 0, 0, 0);  \
    acc[(rb)+3][1] = __builtin_amdgcn_mfma_f32_16x16x32_f16(a3, b1, acc[(rb)+3][1], 0, 0, 0);  \
    acc[(rb)+0][2] = __builtin_amdgcn_mfma_f32_16x16x32_f16(a0, b2, acc[(rb)+0][2], 0, 0, 0);  \
    acc[(rb)+1][2] = __builtin_amdgcn_mfma_f32_16x16x32_f16(a1, b2, acc[(rb)+1][2], 0, 0, 0);  \
    acc[(rb)+2][2] = __builtin_amdgcn_mfma_f32_16x16x32_f16(a2, b2, acc[(rb)+2][2], 0, 0, 0);  \
    acc[(rb)+3][2] = __builtin_amdgcn_mfma_f32_16x16x32_f16(a3, b2, acc[(rb)+3][2], 0, 0, 0);  \
    acc[(rb)+0][3] = __builtin_amdgcn_mfma_f32_16x16x32_f16(a0, b3, acc[(rb)+0][3], 0, 0, 0);  \
    acc[(rb)+1][3] = __builtin_amdgcn_mfma_f32_16x16x32_f16(a1, b3, acc[(rb)+1][3], 0, 0, 0);  \
    acc[(rb)+2][3] = __builtin_amdgcn_mfma_f32_16x16x32_f16(a2, b3, acc[(rb)+2][3], 0, 0, 0);  \
    acc[(rb)+3][3] = __builtin_amdgcn_mfma_f32_16x16x32_f16(a3, b3, acc[(rb)+3][3], 0, 0, 0);  \
  } while (0)

// One K-tile: 4 phases. VM1 placed end-P1, VM4 end-P4 (before the barrier).
#define TILE(BO, ISSUE_STMT, VM1_STMT, VM4_STMT) do {                                     \
    /* P1: ks0, mh0 (+ prefetch whole next tile) */                                       \
    a0=LDA(BO,0,0,cp0); a1=LDA(BO,0,1,cp0); a2=LDA(BO,0,2,cp0); a3=LDA(BO,0,3,cp0);       \
    b0=LDB(BO,0,cp0);   b1=LDB(BO,1,cp0);   b2=LDB(BO,2,cp0);   b3=LDB(BO,3,cp0);         \
    ISSUE_STMT;                                                                           \
    BAR(); LGKM0();                                                                       \
    __builtin_amdgcn_s_setprio(1); MFMA16(0); __builtin_amdgcn_s_setprio(0);              \
    VM1_STMT; BAR();                                                                      \
    /* P2: ks0, mh1 (B frags reused) */                                                   \
    a0=LDA(BO,1,0,cp0); a1=LDA(BO,1,1,cp0); a2=LDA(BO,1,2,cp0); a3=LDA(BO,1,3,cp0);       \
    BAR(); LGKM0();                                                                       \
    __builtin_amdgcn_s_setprio(1); MFMA16(4); __builtin_amdgcn_s_setprio(0);              \
    BAR();                                                                                \
    /* P3: ks1, mh1 */                                                                    \
    a0=LDA(BO,1,0,cp1); a1=LDA(BO,1,1,cp1); a2=LDA(BO,1,2,cp1); a3=LDA(BO,1,3,cp1);       \
    b0=LDB(BO,0,cp1);   b1=LDB(BO,1,cp1);   b2=LDB(BO,2,cp1);   b3=LDB(BO,3,cp1);         \
    BAR(); LGKM0();                                                                       \
    __builtin_amdgcn_s_setprio(1); MFMA16(4); __builtin_amdgcn_s_setprio(0);              \
    BAR();                                                                                \
    /* P4: ks1, mh0 (B frags reused) */                                                   \
    a0=LDA(BO,0,0,cp1); a1=LDA(BO,0,1,cp1); a2=LDA(BO,0,2,cp1); a3=LDA(BO,0,3,cp1);       \
    BAR(); LGKM0();                                                                       \
    __builtin_amdgcn_s_setprio(1); MFMA16(0); __builtin_amdgcn_s_setprio(0);              \
    VM4_STMT; BAR();                                                                      \
  } while (0)

__global__ __launch_bounds__(512, 2) void gemm_f16_kernel(
        const _Float16* __restrict__ A, const _Float16* __restrict__ B,
        const float* __restrict__ bias, float* __restrict__ C) {
    __shared__ __align__(16) char lds[131072];   // 2 bufs x (A 32KB + B 32KB)

    const int tid  = threadIdx.x;
    const int lane = tid & 63;
    const int wave = tid >> 6;      // 0..7
    const int wm   = wave >> 2;     // 0..1 : M-half of block
    const int wn   = wave & 3;      // 0..3 : N-quarter of block
    const int l15  = lane & 15;
    const int kq   = lane >> 4;     // 0..3 : k-chunk of the MFMA fragment

    // bijective XCD swizzle (1376 = 8*172), then n-fastest within 4 m-rows/XCD.
    const int bid = blockIdx.x;
    const int swz = (bid & 7) * 172 + (bid >> 3);
    const int mT  = swz / N_TILES;
    const int nT  = swz - mT * N_TILES;
    const int rowStart = mT << 8;
    const int colStart = nT << 8;

    // ---- staging: linear LDS dest, pre-swizzled global source ----
    // thread feeds 16B chunks p = tid (row r0) and tid+512 (row r0+64) of each
    // 128-row half; dest chunk c' = tid&7, source chunk c = c' ^ (row&7).
    const int r0   = tid >> 3;                    // 0..63
    const int cSrc = (tid & 7) ^ (r0 & 7);
    const _Float16* aS = A + (size_t)(rowStart + r0) * K_DIM + cSrc * 8;
    const _Float16* bS = B + (size_t)(colStart + r0) * K_DIM + cSrc * 8;
    const int stW = wave * 1024;                  // wave slot inside each 8KB region

    // ---- ds_read fragment offsets (bytes) ----
    // row = mh*128 + wm*64 + m*16 + l15 ; chunk c = ks*4+kq ; c' = c ^ (lane&7)
    const int cp0 = ((kq)     ^ (lane & 7)) << 4;
    const int cp1 = ((4 + kq) ^ (lane & 7)) << 4;
    const int aRd = (wm * 64 + l15) * 128;                 // + mh*16384 + m*2048 + cp
    const int bRd = (wn * 32 + l15) * 128 + 32768;         // + (q>>1)*16384 + (q&1)*2048 + cp

    floatx4 acc[8][4];
    const floatx4 z4 = {0.f, 0.f, 0.f, 0.f};
#pragma unroll
    for (int i = 0; i < 8; ++i)
#pragma unroll
        for (int j = 0; j < 4; ++j) acc[i][j] = z4;

    half8 a0, a1, a2, a3, b0, b1, b2, b3;

    // prologue: tile 0 into buf0; need A_h0,B_h0,B_h1 (first 6 loads) landed.
    ISSUE_TILE(0, 0);
    VMW(2);
    BAR();

    // tiles 0..61 in pairs (buffer parity compile-time), prefetch t+1 at P1.
#pragma unroll 1
    for (int t = 0; t < K_TILES - 2; t += 2) {
        const int ko1 = (t + 1) * 64;
        const int ko2 = (t + 2) * 64;
        TILE(0,     ISSUE_TILE(65536, ko1), VMW(8), VMW(2));
        TILE(65536, ISSUE_TILE(0,     ko2), VMW(8), VMW(2));
    }
    // tile 62 (buf0), prefetch last tile into buf1
    TILE(0,     ISSUE_TILE(65536, (K_TILES - 1) * 64), VMW(8), VMW(2));
    // tile 63 (buf1), nothing left to prefetch; drain remaining 2 loads at P1.
    TILE(65536, (void)0, VMW(0), (void)0);

    // ---- epilogue: C/D layout col=lane&15, row=(lane>>4)*4+reg ----
    const int cRow = kq * 4;
#pragma unroll
    for (int r = 0; r < 8; ++r) {
        const int gm = rowStart + (r >> 2) * 128 + wm * 64 + (r & 3) * 16 + cRow;
#pragma unroll
        for (int q = 0; q < 4; ++q) {
            const int gn = colStart + (q >> 1) * 128 + wn * 32 + (q & 1) * 16 + l15;
            const float bv = bias[gn];
            float* cptr = C + (size_t)gm * N_DIM + gn;
#pragma unroll
            for (int e = 0; e < 4; ++e)
                cptr[(size_t)e * N_DIM] = acc[r][q][e] + bv;
        }
    }
}

// ------------------------------- launch ------------------------------------

extern "C" void kernel_launch(void* const* d_in, const int* in_sizes, int n_in,
                              void* d_out, int out_size, void* d_ws, size_t ws_size,
                              hipStream_t stream) {
    const float* x    = (const float*)d_in[0];   // [2,4096,4096]
    const float* W    = (const float*)d_in[1];   // [11008,4096]
    const float* bias = (const float*)d_in[2];   // [11008]
    float* out = (float*)d_out;                  // [2,4096,11008]

    _Float16* Aq = (_Float16*)d_ws;                          // 64MB
    _Float16* Wq = Aq + (size_t)M_DIM * K_DIM;               // 86MB

    prep_kernel<<<QUANT_BLOCKS + CONV_BLOCKS, 256, 0, stream>>>(x, Aq, W, Wq);
    gemm_f16_kernel<<<M_TILES * N_TILES, 512, 0, stream>>>(Aq, Wq, bias, out);
}